// Round 5
// baseline (13579.947 us; speedup 1.0000x reference)
//
#include <hip/hip_runtime.h>
#include <stdint.h>

// SimpleGRU  B=64 S=2048 I=256 H=512 O=10
//
// Phase A (proj_mfma): xp2[g][s][1536][16] (bf16) = x@[Wz|Wr|Wh]^T + (b+c), bf16 MFMA GEMM.
// Phase B (gru_recur): persistent 64 blocks = 4 groups(16 batches) x 16 col-slices(32 cols),
//   U weight-stationary in VGPRs, MFMA 16x16x32.
//   R2: __threadfence = L2 wb+inv (29 us/step) -> all cross-block data via relaxed agent-scope
//       (cache-bypassing) atomics, no fences.
//   R4: separate flag barrier = 1 extra fabric RTT/phase; 64B/thread staging = 16-way LDS conflict.
//   R5: DATA-AS-FLAG: |h|<=1, |r*h|<=1 -> bf16 0x7F7F (3.4e38) is an impossible value. Exchange
//       buffers pre-filled with sentinel; consumers poll the data qwords directly (retry while
//       sentinel). 4-slot rotation; producers re-sentinel slot (t+2) after storing slot t;
//       s_waitcnt vmcnt(0) BEFORE each data-store batch orders sentinels < next data (free, since
//       prior stores landed ~2us ago). No flags, no group barrier, 2 __syncthreads/step.
//       Staging: 4x16B chunks/thread, lane-contiguous (conflict-free b128). Packed qword stores.

#define S_LEN  2048
#define BATCH  64
#define IDIM   256
#define HDIM   512
#define ODIM   10
#define GATES3 1536

#define SENT32 0x7F7F7F7Fu
#define SENT64 0x7F7F7F7F7F7F7F7FULL

typedef __attribute__((ext_vector_type(8))) short bf16x8;
typedef __attribute__((ext_vector_type(4))) float f32x4;

__device__ __forceinline__ unsigned short f2bf(float x) {
    unsigned int u = __float_as_uint(x);
    u += 0x7fffu + ((u >> 16) & 1u);      // RNE
    return (unsigned short)(u >> 16);
}
__device__ __forceinline__ float bf2f(unsigned short h) {
    return __uint_as_float(((unsigned int)h) << 16);
}

// Cache-bypassing device-coherent accesses (relaxed agent atomics -> sc0 sc1 global ops).
__device__ __forceinline__ unsigned long long g_load64(const void* p) {
    return __hip_atomic_load((const unsigned long long*)p, __ATOMIC_RELAXED, __HIP_MEMORY_SCOPE_AGENT);
}
__device__ __forceinline__ void g_store32(void* p, unsigned int v) {
    __hip_atomic_store((unsigned int*)p, v, __ATOMIC_RELAXED, __HIP_MEMORY_SCOPE_AGENT);
}
__device__ __forceinline__ void g_store64(void* p, unsigned long long v) {
    __hip_atomic_store((unsigned long long*)p, v, __ATOMIC_RELAXED, __HIP_MEMORY_SCOPE_AGENT);
}

// ---------------------------------------------------------------------------
// Phase A: bf16 MFMA GEMM. Tile 128(m) x 128(n), K-panels of 64, frag-major LDS.
// m = s*64 + b; grid(12 n-tiles, 1024 m-tiles), 256 threads.
// ---------------------------------------------------------------------------
__global__ __launch_bounds__(256)
void proj_mfma(const float* __restrict__ x,
               const float* __restrict__ Wz, const float* __restrict__ Wr, const float* __restrict__ Wh,
               const float* __restrict__ bz, const float* __restrict__ cz,
               const float* __restrict__ br, const float* __restrict__ cr,
               const float* __restrict__ bh, const float* __restrict__ ch,
               unsigned short* __restrict__ xp2)
{
    __shared__ unsigned short As[8 * 128 * 8];   // [kcq][row][e]  16 KB
    __shared__ unsigned short Bs[8 * 128 * 8];   // 16 KB
    const int tid  = threadIdx.x;
    const int wave = tid >> 6;
    const int lane = tid & 63;
    const int quad = lane >> 4;
    const int l16  = lane & 15;
    const int nt_ = blockIdx.x;   // 0..11
    const int mt_ = blockIdx.y;   // 0..1023

    const int srow  = tid >> 1;
    const int shalf = tid & 1;
    const int mg = mt_ * 128 + srow;
    const float* axrow = x + ((size_t)(mg & 63) * S_LEN + (mg >> 6)) * IDIM + shalf * 32;
    const int ng = nt_ * 128 + srow;
    const int gt = ng >> 9, hl = ng & 511;
    const float* bxrow = (gt == 0 ? Wz : gt == 1 ? Wr : Wh) + (size_t)hl * IDIM + shalf * 32;

    f32x4 acc[2][8];
#pragma unroll
    for (int mi = 0; mi < 2; ++mi)
#pragma unroll
        for (int nj = 0; nj < 8; ++nj) {
            f32x4 z = {0.f, 0.f, 0.f, 0.f};
            acc[mi][nj] = z;
        }

    for (int kp = 0; kp < IDIM; kp += 64) {
#pragma unroll
        for (int c = 0; c < 4; ++c) {
            unsigned short ta[8], tb[8];
#pragma unroll
            for (int e = 0; e < 8; ++e) {
                ta[e] = f2bf(axrow[kp + c * 8 + e]);
                tb[e] = f2bf(bxrow[kp + c * 8 + e]);
            }
            const int kcq = shalf * 4 + c;
            *(bf16x8*)(As + (kcq * 128 + srow) * 8) = *(bf16x8*)ta;
            *(bf16x8*)(Bs + (kcq * 128 + srow) * 8) = *(bf16x8*)tb;
        }
        __syncthreads();
#pragma unroll
        for (int kc = 0; kc < 2; ++kc) {
            bf16x8 af[2], bfr[8];
#pragma unroll
            for (int mi = 0; mi < 2; ++mi)
                af[mi] = *(const bf16x8*)(As + ((kc * 4 + quad) * 128 + wave * 32 + mi * 16 + l16) * 8);
#pragma unroll
            for (int nj = 0; nj < 8; ++nj)
                bfr[nj] = *(const bf16x8*)(Bs + ((kc * 4 + quad) * 128 + nj * 16 + l16) * 8);
#pragma unroll
            for (int mi = 0; mi < 2; ++mi)
#pragma unroll
                for (int nj = 0; nj < 8; ++nj)
                    acc[mi][nj] = __builtin_amdgcn_mfma_f32_16x16x32_bf16(af[mi], bfr[nj], acc[mi][nj], 0, 0, 0);
        }
        __syncthreads();
    }

    const int s_ = mt_ * 2 + (wave >> 1);
#pragma unroll
    for (int nj = 0; nj < 8; ++nj) {
        const int n  = nt_ * 128 + nj * 16 + l16;
        const int g2 = n >> 9, h2 = n & 511;
        const float bias = (g2 == 0 ? bz[h2] + cz[h2]
                          : g2 == 1 ? br[h2] + cr[h2]
                                    : bh[h2] + ch[h2]);
#pragma unroll
        for (int mi = 0; mi < 2; ++mi) {
            const int gg = (wave & 1) * 2 + mi;
            unsigned short pk[4];
#pragma unroll
            for (int r = 0; r < 4; ++r) pk[r] = f2bf(acc[mi][nj][r] + bias);
            *(unsigned long long*)(xp2 + (((size_t)gg * S_LEN + s_) * GATES3 + n) * 16 + quad * 4) =
                *(unsigned long long*)pk;
        }
    }
}

// ---------------------------------------------------------------------------
// Frag-major state layout per 16-KB slot (16 rows x 512 cols bf16):
//   idx(row, col) = (col>>5)*512 + ((col>>3)&3)*128 + row*8 + (col&7)   [shorts]
// Stage with sentinel-poll: each thread copies 4 chunks of 16 B, lane-contiguous.
// ---------------------------------------------------------------------------
__device__ __forceinline__ void stage_poll(const unsigned short* __restrict__ gsrc,
                                           unsigned short* __restrict__ lds, int tid)
{
    unsigned long long v[8];
#pragma unroll
    for (int i = 0; i < 8; ++i)
        v[i] = g_load64(gsrc + (i >> 1) * 2048 + tid * 8 + (i & 1) * 4);
    while (true) {
        unsigned pend = 0;
#pragma unroll
        for (int i = 0; i < 8; ++i)
            if (((unsigned)v[i]) == SENT32 || ((unsigned)(v[i] >> 32)) == SENT32)
                pend |= 1u << i;
        if (!pend) break;
#pragma unroll
        for (int i = 0; i < 8; ++i)
            if (pend & (1u << i))
                v[i] = g_load64(gsrc + (i >> 1) * 2048 + tid * 8 + (i & 1) * 4);
    }
#pragma unroll
    for (int sgm = 0; sgm < 4; ++sgm) {
        unsigned long long* q = (unsigned long long*)(lds + sgm * 2048 + tid * 8);
        q[0] = v[2 * sgm];
        q[1] = v[2 * sgm + 1];
    }
}

// ---------------------------------------------------------------------------
// Phase B: 64 blocks: g = blockIdx&3 (batches 16g..), j = blockIdx>>2 (cols 32j..).
// Waves: w0,w1 = z (nt 0/1) then h~ + update; w2,w3 = r (nt 0/1).
// hg/rhg: [slot 0..3][group 0..3][8192 shorts] rotating sentinel-synced exchange buffers.
// ---------------------------------------------------------------------------
__global__ __launch_bounds__(256)
void gru_recur(const float* __restrict__ Uz, const float* __restrict__ Ur,
               const float* __restrict__ Uh,
               const unsigned short* __restrict__ xp2,  // [g][s][1536][16] bf16
               unsigned short* __restrict__ hg,         // h slots   (init: s0-2 SENT, s3 = 0)
               unsigned short* __restrict__ rhg,        // r*h slots (init: all SENT)
               float* __restrict__ hgf,                 // fp32 final h [64][512] (init SENT)
               const float* __restrict__ Wf, const float* __restrict__ bfv,
               float* __restrict__ out)
{
    __shared__ unsigned short ldsA[8192];   // staged h_{t-1}
    __shared__ unsigned short ldsB[8192];   // staged r*h
    const int tid  = threadIdx.x;
    const int wave = tid >> 6;
    const int lane = tid & 63;
    const int quad = lane >> 4;
    const int l16  = lane & 15;
    const int g  = blockIdx.x & 3;
    const int j  = blockIdx.x >> 2;
    const int b0 = g * 16;
    const int i0 = j * 32;
    const int nt = wave & 1;
    const bool isZ = (wave < 2);

    // ---- weight B-fragments, stationary in VGPRs ----
    const int wrow = i0 + nt * 16 + l16;   // n = lane&15
    const int kofs = quad * 8;
    bf16x8 wp1[16], wp2[16];
    const float* U1 = isZ ? Uz : Ur;
#pragma unroll
    for (int kb = 0; kb < 16; ++kb) {
        const float* s1 = U1 + (size_t)wrow * HDIM + kb * 32 + kofs;
        const float* s2 = Uh + (size_t)wrow * HDIM + kb * 32 + kofs;
        bf16x8 w1, w2;
#pragma unroll
        for (int e = 0; e < 8; ++e) {
            w1[e] = (short)f2bf(s1[e]);
            w2[e] = (short)f2bf(s2[e]);
        }
        wp1[kb] = w1; wp2[kb] = w2;
    }

    const int iloc = nt * 16 + l16;
    const int icol = i0 + iloc;
    // frag-major indices
    const int pfull = (icol >> 5) * 512 + ((icol >> 3) & 3) * 128 + (icol & 7);  // + row*8
    const int qbase = (icol >> 5) * 512 + ((icol >> 3) & 3) * 128 + (icol & 4);  // qword base
    const bool qlane = ((l16 & 3) == 0);
    const unsigned short* xpg = xp2 + (size_t)g * S_LEN * GATES3 * 16;
    const int gofs1 = isZ ? 0 : HDIM;

    float zfrag[4];
    float hm[4] = {0.f, 0.f, 0.f, 0.f};   // fp32 master h (w0/w1)

    // prefetch xp for t=0 (normal cached loads; xp2 visible via kernel-boundary flush)
    unsigned long long xg_cur = *(const unsigned long long*)
        (xpg + ((size_t)0 * GATES3 + gofs1 + icol) * 16 + quad * 4);
    unsigned long long xh_cur = *(const unsigned long long*)
        (xpg + ((size_t)0 * GATES3 + 2 * HDIM + icol) * 16 + quad * 4);

    for (int t = 0; t < S_LEN; ++t) {
        // ================= PHASE 1: consume h_{t-1}, produce z / r*h =================
        const unsigned short* hsrc = hg + ((((t + 3) & 3) * 4 + g) * 8192);
        stage_poll(hsrc, ldsA, tid);
        __syncthreads();                         // ldsA written (also protects ldsB reuse)

        f32x4 ca = {0.f, 0.f, 0.f, 0.f}, cb = {0.f, 0.f, 0.f, 0.f};
#pragma unroll
        for (int kb = 0; kb < 16; kb += 2) {
            const bf16x8 a0 = *(const bf16x8*)(ldsA + kb * 512 + quad * 128 + l16 * 8);
            const bf16x8 a1 = *(const bf16x8*)(ldsA + (kb + 1) * 512 + quad * 128 + l16 * 8);
            ca = __builtin_amdgcn_mfma_f32_16x16x32_bf16(a0, wp1[kb], ca, 0, 0, 0);
            cb = __builtin_amdgcn_mfma_f32_16x16x32_bf16(a1, wp1[kb + 1], cb, 0, 0, 0);
        }
        union { unsigned long long q; unsigned short s[4]; } xq;
        xq.q = xg_cur;

        if (isZ) {
#pragma unroll
            for (int r = 0; r < 4; ++r) {
                const float pre = ca[r] + cb[r] + bf2f(xq.s[r]);
                zfrag[r] = 1.f / (1.f + __expf(-pre));
            }
        } else {
            float rhv[4];
#pragma unroll
            for (int r = 0; r < 4; ++r) {
                const float pre = ca[r] + cb[r] + bf2f(xq.s[r]);
                const float v = 1.f / (1.f + __expf(-pre));
                rhv[r] = v * bf2f(ldsA[pfull + (quad * 4 + r) * 8]);   // h_{t-1} (bf16)
            }
            // order: prior-step stores (incl. sentinels) landed before these stores issue
            __builtin_amdgcn_s_waitcnt(0x0F70);    // vmcnt(0)
            unsigned short* ds = rhg + (((t & 3) * 4 + g) * 8192) + qbase;
            unsigned short* ss = rhg + ((((t + 2) & 3) * 4 + g) * 8192) + qbase;
#pragma unroll
            for (int r = 0; r < 4; ++r) {
                unsigned my = f2bf(rhv[r]);
                unsigned ot = (unsigned)__shfl_xor((int)my, 1, 64);
                unsigned d  = my | (ot << 16);
                unsigned d2 = (unsigned)__shfl_xor((int)d, 2, 64);
                if (qlane)
                    g_store64(ds + (quad * 4 + r) * 8,
                              (unsigned long long)d | ((unsigned long long)d2 << 32));
            }
#pragma unroll
            for (int r = 0; r < 4; ++r)
                if (qlane) g_store64(ss + (quad * 4 + r) * 8, SENT64);
            // prefetch next xr
            const int tn1 = (t + 1 < S_LEN) ? t + 1 : t;
            xg_cur = *(const unsigned long long*)
                (xpg + ((size_t)tn1 * GATES3 + gofs1 + icol) * 16 + quad * 4);
        }

        // ================= PHASE 2: consume r*h, produce h_t =================
        const unsigned short* rsrc = rhg + (((t & 3) * 4 + g) * 8192);
        stage_poll(rsrc, ldsB, tid);
        __syncthreads();                         // ldsB written (also protects ldsA reuse)

        if (isZ) {
            f32x4 c2a = {0.f, 0.f, 0.f, 0.f}, c2b = {0.f, 0.f, 0.f, 0.f};
#pragma unroll
            for (int kb = 0; kb < 16; kb += 2) {
                const bf16x8 a0 = *(const bf16x8*)(ldsB + kb * 512 + quad * 128 + l16 * 8);
                const bf16x8 a1 = *(const bf16x8*)(ldsB + (kb + 1) * 512 + quad * 128 + l16 * 8);
                c2a = __builtin_amdgcn_mfma_f32_16x16x32_bf16(a0, wp2[kb], c2a, 0, 0, 0);
                c2b = __builtin_amdgcn_mfma_f32_16x16x32_bf16(a1, wp2[kb + 1], c2b, 0, 0, 0);
            }
            union { unsigned long long q; unsigned short s[4]; } xh;
            xh.q = xh_cur;
            float hn[4];
#pragma unroll
            for (int r = 0; r < 4; ++r) {
                const float pre = c2a[r] + c2b[r] + bf2f(xh.s[r]);
                const float ht = tanhf(pre);
                hn[r] = hm[r] + zfrag[r] * (ht - hm[r]);
                hm[r] = hn[r];
            }
            __builtin_amdgcn_s_waitcnt(0x0F70);    // vmcnt(0): order prior sentinels < new data
            unsigned short* ds = hg + (((t & 3) * 4 + g) * 8192) + qbase;
            unsigned short* ss = hg + ((((t + 2) & 3) * 4 + g) * 8192) + qbase;
#pragma unroll
            for (int r = 0; r < 4; ++r) {
                unsigned my = f2bf(hn[r]);
                unsigned ot = (unsigned)__shfl_xor((int)my, 1, 64);
                unsigned d  = my | (ot << 16);
                unsigned d2 = (unsigned)__shfl_xor((int)d, 2, 64);
                if (qlane)
                    g_store64(ds + (quad * 4 + r) * 8,
                              (unsigned long long)d | ((unsigned long long)d2 << 32));
            }
#pragma unroll
            for (int r = 0; r < 4; ++r)
                if (qlane) g_store64(ss + (quad * 4 + r) * 8, SENT64);
            if (t == S_LEN - 1) {
#pragma unroll
                for (int r = 0; r < 4; ++r)
                    g_store32(hgf + (size_t)(b0 + quad * 4 + r) * HDIM + icol,
                              __float_as_uint(hn[r]));
            }
            // prefetch next xz, xh
            const int tn1 = (t + 1 < S_LEN) ? t + 1 : t;
            xg_cur = *(const unsigned long long*)
                (xpg + ((size_t)tn1 * GATES3 + gofs1 + icol) * 16 + quad * 4);
            xh_cur = *(const unsigned long long*)
                (xpg + ((size_t)tn1 * GATES3 + 2 * HDIM + icol) * 16 + quad * 4);
        }
    }

    // ---- final projection: out = h_T @ Wf^T + bf (poll fp32 sentinels) ----
    if (j == 0 && tid < 16 * ODIM) {
        const int b = b0 + tid / ODIM;
        const int o = tid % ODIM;
        float acc = bfv[o];
        for (int k = 0; k < HDIM; k += 2) {
            union { unsigned long long q; float f[2]; unsigned u[2]; } w;
            w.q = g_load64(hgf + (size_t)b * HDIM + k);
            while (w.u[0] == SENT32 || w.u[1] == SENT32)
                w.q = g_load64(hgf + (size_t)b * HDIM + k);
            acc += w.f[0] * Wf[o * HDIM + k] + w.f[1] * Wf[o * HDIM + k + 1];
        }
        out[b * ODIM + o] = acc;
    }
}

// ---------------------------------------------------------------------------
extern "C" void kernel_launch(void* const* d_in, const int* in_sizes, int n_in,
                              void* d_out, int out_size, void* d_ws, size_t ws_size,
                              hipStream_t stream)
{
    const float* x  = (const float*)d_in[0];
    const float* Wz = (const float*)d_in[1];
    const float* bz = (const float*)d_in[2];
    const float* Uz = (const float*)d_in[3];
    const float* cz = (const float*)d_in[4];
    const float* Wr = (const float*)d_in[5];
    const float* br = (const float*)d_in[6];
    const float* Ur = (const float*)d_in[7];
    const float* cr = (const float*)d_in[8];
    const float* Wh = (const float*)d_in[9];
    const float* bh = (const float*)d_in[10];
    const float* Uh = (const float*)d_in[11];
    const float* ch = (const float*)d_in[12];
    const float* Wf = (const float*)d_in[13];
    const float* bf = (const float*)d_in[14];
    float* out = (float*)d_out;

    char* ws = (char*)d_ws;
    const size_t XPB = (size_t)S_LEN * BATCH * GATES3 * sizeof(unsigned short); // 402,653,184 B
    unsigned short* xp2 = (unsigned short*)ws;
    unsigned short* hg  = (unsigned short*)(ws + XPB);            // 4 slots x 4 groups x 16 KB = 256 KB
    unsigned short* rhg = (unsigned short*)(ws + XPB + 262144);   // 256 KB
    float*          hgf = (float*)(ws + XPB + 524288);            // 128 KB
    // total: XPB + 655,360 B

    // sentinel/zero init (h0 = 0 lives in hg slot 3)
    hipMemsetAsync(ws + XPB, 0x7F, 196608, stream);               // hg slots 0..2 = SENT
    hipMemsetAsync(ws + XPB + 196608, 0x00, 65536, stream);       // hg slot 3 = h0 = 0
    hipMemsetAsync(ws + XPB + 262144, 0x7F, 262144 + 131072, stream);  // rhg + hgf = SENT

    proj_mfma<<<dim3(12, 1024), 256, 0, stream>>>(
        x, Wz, Wr, Wh, bz, cz, br, cr, bh, ch, xp2);

    gru_recur<<<dim3(64), dim3(256), 0, stream>>>(
        Uz, Ur, Uh, xp2, hg, rhg, hgf, Wf, bf, out);
}